// Round 5
// baseline (89.336 us; speedup 1.0000x reference)
//
#include <hip/hip_runtime.h>
#include <hip/hip_bf16.h>

#define NB 16384
#define NT 32
#define NI 27
#define NH 32
#define NG 26

typedef __attribute__((ext_vector_type(8))) short bf16x8;
typedef __attribute__((ext_vector_type(4))) float f32x4;
typedef __attribute__((ext_vector_type(4))) int   i32x4;

#define MFMA(a, b, c) __builtin_amdgcn_mfma_f32_16x16x32_bf16((a), (b), (c), 0, 0, 0)

static __device__ __forceinline__ int pack2(float lo, float hi) {
    unsigned short a = __builtin_bit_cast(unsigned short, __float2bfloat16(lo));
    unsigned short b = __builtin_bit_cast(unsigned short, __float2bfloat16(hi));
    return (int)(((unsigned)b << 16) | (unsigned)a);
}

static __device__ __forceinline__ float sigm(float x) {
    return __builtin_amdgcn_rcpf(1.0f + __expf(-x));
}
static __device__ __forceinline__ float tanh_(float x) {
    return 2.0f * __builtin_amdgcn_rcpf(1.0f + __expf(-2.0f * x)) - 1.0f;
}

// MFMA A-fragment: lane (bl,g4) supplies row=bl(+tile), k=8*g4+j from row-major
// W[nrows][rowlen], zero-padded outside. Verified mapping (R2/R4 passed).
static __device__ __forceinline__ bf16x8 load_wfrag(const float* __restrict__ W,
                                                    int rowlen, int nrows, int row, int k0) {
    int w[4];
#pragma unroll
    for (int q = 0; q < 4; ++q) {
        int k = k0 + 2 * q;
        float lo = (row < nrows && k     < rowlen) ? W[row * rowlen + k]     : 0.0f;
        float hi = (row < nrows && k + 1 < rowlen) ? W[row * rowlen + k + 1] : 0.0f;
        w[q] = pack2(lo, hi);
    }
    i32x4 v = { w[0], w[1], w[2], w[3] };
    return __builtin_bit_cast(bf16x8, v);
}

// 2 waves per block: wave s owns hidden units [16s, 16s+16) of all 4 gates
// (gate-row m = 2*gate + s). Per layer the 16x32 bf16 h-tile is exchanged
// through LDS (write own half -> barrier -> read full K as B-fragment).
__global__ __launch_bounds__(128, 2)
void lstm_split(const float* __restrict__ X,   // [B,T,I] flat, consumed as [T,B,I]
                const float* __restrict__ Gu,  // [B,26]
                const float* __restrict__ H0, const float* __restrict__ C0,
                const float* __restrict__ Wih0, const float* __restrict__ Whh0,
                const float* __restrict__ bih0, const float* __restrict__ bhh0,
                const float* __restrict__ Wih1, const float* __restrict__ Whh1,
                const float* __restrict__ bih1, const float* __restrict__ bhh1,
                const float* __restrict__ Wfc, const float* __restrict__ bfc,
                float* __restrict__ out)
{
    const int lane = threadIdx.x & 63;
    const int s    = threadIdx.x >> 6;   // hidden-half this wave owns
    const int bl   = lane & 15;          // batch slot (MFMA col)
    const int g4   = lane >> 4;
    const int k0   = 8 * g4;             // K-offset this lane supplies to A/B frags
    const int batch = blockIdx.x * 16 + bl;

    __shared__ unsigned int hb[2][16][16];  // [layer][batch][k-pair] bf16x2

    // ---------- persistent weights (4 gate-row groups per wave) ----------
    bf16x8 A0x[4], A0h[4], A1i[4], A1h[4];
    f32x4  b0[4], b1[4];
#pragma unroll
    for (int j = 0; j < 4; ++j) {          // j = gate (i,f,g,o)
        int m = 2 * j + s;                 // MFMA row-tile index
        A0x[j] = load_wfrag(Wih0, NI, 4 * NH, 16 * m + bl, k0);
        A0h[j] = load_wfrag(Whh0, NH, 4 * NH, 16 * m + bl, k0);
        A1i[j] = load_wfrag(Wih1, NH, 4 * NH, 16 * m + bl, k0);
        A1h[j] = load_wfrag(Whh1, NH, 4 * NH, 16 * m + bl, k0);
#pragma unroll
        for (int r = 0; r < 4; ++r) {
            int gr = 16 * m + 4 * g4 + r;  // gate row; hidden = 16s+4g4+r
            b0[j][r] = bih0[gr] + bhh0[gr];
            b1[j][r] = bih1[gr] + bhh1[gr];
        }
    }
    // FC: wave s computes logit rows 16s+4g4+r
    bf16x8 Afc0 = load_wfrag(Wfc, NH + NG, NG, 16 * s + bl, k0);
    bf16x8 Afc1 = load_wfrag(Wfc, NH + NG, NG, 16 * s + bl, NH + k0);

    // ---------- state init (init aliases h0/c0 for both layers) ----------
    const float* h0p = H0 + (size_t)batch * NH;
    const float* c0p = C0 + (size_t)batch * NH;
    int hw[4];
#pragma unroll
    for (int q = 0; q < 4; ++q) hw[q] = pack2(h0p[k0 + 2 * q], h0p[k0 + 2 * q + 1]);
    i32x4 hv = { hw[0], hw[1], hw[2], hw[3] };
    bf16x8 h1f = __builtin_bit_cast(bf16x8, hv);
    bf16x8 h2f = h1f;
    float c1[4], c2[4], hsum[4];
#pragma unroll
    for (int r = 0; r < 4; ++r) {
        float c = c0p[16 * s + 4 * g4 + r];
        c1[r] = c; c2[r] = c; hsum[r] = 0.0f;
    }

    // x prefetch (t=0): lane supplies x[batch][k0..k0+7], zero-padded past NI
    float xn[8];
    {
        const float* xp = X + (size_t)batch * NI;
#pragma unroll
        for (int j = 0; j < 8; ++j) { int k = k0 + j; xn[j] = (k < NI) ? xp[k] : 0.0f; }
    }

    const int wr = 8 * s + 2 * g4;   // k-pair write index for own hidden half

#pragma unroll 1
    for (int t = 0; t < NT; ++t) {
        int xw[4];
#pragma unroll
        for (int q = 0; q < 4; ++q) xw[q] = pack2(xn[2 * q], xn[2 * q + 1]);
        i32x4 xv = { xw[0], xw[1], xw[2], xw[3] };
        bf16x8 xf = __builtin_bit_cast(bf16x8, xv);
        if (t + 1 < NT) {
            const float* xp = X + ((size_t)(t + 1) * NB + batch) * NI;
#pragma unroll
            for (int j = 0; j < 8; ++j) { int k = k0 + j; xn[j] = (k < NI) ? xp[k] : 0.0f; }
        }

        // ---------- layer 0 ----------
        f32x4 g[4];
#pragma unroll
        for (int j = 0; j < 4; ++j) g[j] = MFMA(A0x[j], xf, b0[j]);
#pragma unroll
        for (int j = 0; j < 4; ++j) g[j] = MFMA(A0h[j], h1f, g[j]);
        float hn[4];
#pragma unroll
        for (int r = 0; r < 4; ++r) {
            float iv = sigm(g[0][r]);
            float fv = sigm(g[1][r]);
            float gv = tanh_(g[2][r]);
            float ov = sigm(g[3][r]);
            c1[r] = fmaf(fv, c1[r], iv * gv);
            hn[r] = ov * tanh_(c1[r]);
        }
        // exchange h1: write own half, barrier, read full K
        *(uint2*)&hb[0][bl][wr] = make_uint2((unsigned)pack2(hn[0], hn[1]),
                                             (unsigned)pack2(hn[2], hn[3]));
        __syncthreads();
        h1f = __builtin_bit_cast(bf16x8, *(const i32x4*)&hb[0][bl][4 * g4]);

        // ---------- layer 1 ----------
#pragma unroll
        for (int j = 0; j < 4; ++j) g[j] = MFMA(A1i[j], h1f, b1[j]);
#pragma unroll
        for (int j = 0; j < 4; ++j) g[j] = MFMA(A1h[j], h2f, g[j]);
#pragma unroll
        for (int r = 0; r < 4; ++r) {
            float iv = sigm(g[0][r]);
            float fv = sigm(g[1][r]);
            float gv = tanh_(g[2][r]);
            float ov = sigm(g[3][r]);
            c2[r] = fmaf(fv, c2[r], iv * gv);
            float h = ov * tanh_(c2[r]);
            hn[r] = h;
            hsum[r] += h;
        }
        *(uint2*)&hb[1][bl][wr] = make_uint2((unsigned)pack2(hn[0], hn[1]),
                                             (unsigned)pack2(hn[2], hn[3]));
        __syncthreads();
        h2f = __builtin_bit_cast(bf16x8, *(const i32x4*)&hb[1][bl][4 * g4]);
    }

    // ---------- fc head ----------
    // hb[0]'s last reads completed before the final barrier -> safe to reuse
    *(uint2*)&hb[0][bl][wr] = make_uint2(
        (unsigned)pack2(hsum[0] * (1.0f / NT), hsum[1] * (1.0f / NT)),
        (unsigned)pack2(hsum[2] * (1.0f / NT), hsum[3] * (1.0f / NT)));
    __syncthreads();
    bf16x8 hsf = __builtin_bit_cast(bf16x8, *(const i32x4*)&hb[0][bl][4 * g4]);

    int gw[4];
    {
        const float* gp = Gu + (size_t)batch * NG;
#pragma unroll
        for (int q = 0; q < 4; ++q) {
            int k = k0 + 2 * q;
            float lo = (k     < NG) ? gp[k]     : 0.0f;
            float hi = (k + 1 < NG) ? gp[k + 1] : 0.0f;
            gw[q] = pack2(lo, hi);
        }
    }
    i32x4 gv_ = { gw[0], gw[1], gw[2], gw[3] };
    bf16x8 guf = __builtin_bit_cast(bf16x8, gv_);

    f32x4 zero4 = { 0.0f, 0.0f, 0.0f, 0.0f };
    f32x4 L = MFMA(Afc0, hsf, zero4);
    L = MFMA(Afc1, guf, L);

#pragma unroll
    for (int r = 0; r < 4; ++r) {
        int row = 16 * s + 4 * g4 + r;
        if (row < NG) {
            float v = L[r] + bfc[row];
            out[(size_t)batch * NG + row] = v;
            out[(size_t)NB * NG + (size_t)batch * NG + row] = sigm(v);
        }
    }
}

extern "C" void kernel_launch(void* const* d_in, const int* in_sizes, int n_in,
                              void* d_out, int out_size, void* d_ws, size_t ws_size,
                              hipStream_t stream) {
    const float* X    = (const float*)d_in[0];
    const float* Gu   = (const float*)d_in[1];
    const float* H0   = (const float*)d_in[2];
    const float* C0   = (const float*)d_in[3];
    const float* Wih0 = (const float*)d_in[4];
    const float* Whh0 = (const float*)d_in[5];
    const float* bih0 = (const float*)d_in[6];
    const float* bhh0 = (const float*)d_in[7];
    const float* Wih1 = (const float*)d_in[8];
    const float* Whh1 = (const float*)d_in[9];
    const float* bih1 = (const float*)d_in[10];
    const float* bhh1 = (const float*)d_in[11];
    const float* Wfc  = (const float*)d_in[12];
    const float* bfc  = (const float*)d_in[13];
    float* out = (float*)d_out;

    dim3 grid(NB / 16), block(128);  // 1024 blocks x 2 waves = 2048 waves (2/SIMD)
    hipLaunchKernelGGL(lstm_split, grid, block, 0, stream,
                       X, Gu, H0, C0, Wih0, Whh0, bih0, bhh0,
                       Wih1, Whh1, bih1, bhh1, Wfc, bfc, out);
}

// Round 7
// 79.894 us; speedup vs baseline: 1.1182x; 1.1182x over previous
//
#include <hip/hip_runtime.h>
#include <hip/hip_bf16.h>

#define NB 16384
#define NT 32
#define NI 27
#define NH 32
#define NG 26

typedef __attribute__((ext_vector_type(8))) short bf16x8;
typedef __attribute__((ext_vector_type(4))) float f32x4;
typedef __attribute__((ext_vector_type(4))) int   i32x4;

#define MFMA(a, b, c) __builtin_amdgcn_mfma_f32_16x16x32_bf16((a), (b), (c), 0, 0, 0)

static __device__ __forceinline__ int pack2(float lo, float hi) {
    unsigned short a = __builtin_bit_cast(unsigned short, __float2bfloat16(lo));
    unsigned short b = __builtin_bit_cast(unsigned short, __float2bfloat16(hi));
    return (int)(((unsigned)b << 16) | (unsigned)a);
}

static __device__ __forceinline__ float sigm(float x) {
    return __builtin_amdgcn_rcpf(1.0f + __expf(-x));
}
static __device__ __forceinline__ float tanh_(float x) {
    return 2.0f * __builtin_amdgcn_rcpf(1.0f + __expf(-2.0f * x)) - 1.0f;
}

// MFMA A-fragment: lane (bl,g4) supplies row, k=8*g4+j from row-major
// W[nrows][rowlen], zero-padded outside. Mapping verified (R2/R4 passed).
static __device__ __forceinline__ bf16x8 load_wfrag(const float* __restrict__ W,
                                                    int rowlen, int nrows, int row, int k0) {
    int w[4];
#pragma unroll
    for (int q = 0; q < 4; ++q) {
        int k = k0 + 2 * q;
        float lo = (row < nrows && k     < rowlen) ? W[row * rowlen + k]     : 0.0f;
        float hi = (row < nrows && k + 1 < rowlen) ? W[row * rowlen + k + 1] : 0.0f;
        w[q] = pack2(lo, hi);
    }
    i32x4 v = { w[0], w[1], w[2], w[3] };
    return __builtin_bit_cast(bf16x8, v);
}

// Redistribute h_new (lane holds hn[r][mh] = h[16*mh + 4*g4 + r] of batch bl)
// into the B-fragment layout (lane needs k = 8*g4 + j of batch bl).
// 8x ds_bpermute within the 4-lane group {bl, bl+16, bl+32, bl+48}.
static __device__ __forceinline__ bf16x8 redist(const float hn[4][2], int a0, int a1, bool mhi) {
    int w00 = pack2(hn[0][0], hn[1][0]);
    int w01 = pack2(hn[2][0], hn[3][0]);
    int w10 = pack2(hn[0][1], hn[1][1]);
    int w11 = pack2(hn[2][1], hn[3][1]);
    int q0lo = __builtin_amdgcn_ds_bpermute(a0, w00), q0hi = __builtin_amdgcn_ds_bpermute(a0, w10);
    int q1lo = __builtin_amdgcn_ds_bpermute(a0, w01), q1hi = __builtin_amdgcn_ds_bpermute(a0, w11);
    int q2lo = __builtin_amdgcn_ds_bpermute(a1, w00), q2hi = __builtin_amdgcn_ds_bpermute(a1, w10);
    int q3lo = __builtin_amdgcn_ds_bpermute(a1, w01), q3hi = __builtin_amdgcn_ds_bpermute(a1, w11);
    i32x4 v = { mhi ? q0hi : q0lo, mhi ? q1hi : q1lo, mhi ? q2hi : q2lo, mhi ? q3hi : q3lo };
    return __builtin_bit_cast(bf16x8, v);
}

__global__ __launch_bounds__(256, 1)
void lstm_pipe(const float* __restrict__ X,   // [B,T,I] flat, consumed as [T,B,I]
               const float* __restrict__ Gu,  // [B,26]
               const float* __restrict__ H0, const float* __restrict__ C0,
               const float* __restrict__ Wih0, const float* __restrict__ Whh0,
               const float* __restrict__ bih0, const float* __restrict__ bhh0,
               const float* __restrict__ Wih1, const float* __restrict__ Whh1,
               const float* __restrict__ bih1, const float* __restrict__ bhh1,
               const float* __restrict__ Wfc, const float* __restrict__ bfc,
               float* __restrict__ out)
{
    const int lane = threadIdx.x & 63;
    const int bl   = lane & 15;
    const int g4   = lane >> 4;
    const int k0   = 8 * g4;
    const int wid  = blockIdx.x * (blockDim.x >> 6) + (threadIdx.x >> 6);
    const int batch = wid * 16 + bl;
    const bool mhi = (g4 >> 1) != 0;
    const int a0 = 4 * (bl + 16 * (2 * (g4 & 1)));
    const int a1 = a0 + 64;

    // ---------- persistent weight A-fragments + bias C-init ----------
    bf16x8 A0x[8], A0h[8], A1i[8], A1h[8];
    f32x4  b0[8], b1[8];
#pragma unroll
    for (int m = 0; m < 8; ++m) {
        A0x[m] = load_wfrag(Wih0, NI, 4 * NH, 16 * m + bl, k0);
        A0h[m] = load_wfrag(Whh0, NH, 4 * NH, 16 * m + bl, k0);
        A1i[m] = load_wfrag(Wih1, NH, 4 * NH, 16 * m + bl, k0);
        A1h[m] = load_wfrag(Whh1, NH, 4 * NH, 16 * m + bl, k0);
#pragma unroll
        for (int r = 0; r < 4; ++r) {
            int gr = 16 * m + 4 * g4 + r;
            b0[m][r] = bih0[gr] + bhh0[gr];
            b1[m][r] = bih1[gr] + bhh1[gr];
        }
    }
    bf16x8 Afc0[2], Afc1[2];
#pragma unroll
    for (int m2 = 0; m2 < 2; ++m2) {
        Afc0[m2] = load_wfrag(Wfc, NH + NG, NG, 16 * m2 + bl, k0);
        Afc1[m2] = load_wfrag(Wfc, NH + NG, NG, 16 * m2 + bl, NH + k0);
    }

    // ---------- state init ----------
    const float* h0p = H0 + (size_t)batch * NH;
    const float* c0p = C0 + (size_t)batch * NH;
    int hw[4];
#pragma unroll
    for (int q = 0; q < 4; ++q) hw[q] = pack2(h0p[k0 + 2 * q], h0p[k0 + 2 * q + 1]);
    i32x4 hv = { hw[0], hw[1], hw[2], hw[3] };
    bf16x8 h1f = __builtin_bit_cast(bf16x8, hv);
    bf16x8 h2f = h1f;
    float c1[4][2], c2[4][2], hsum[4][2];
#pragma unroll
    for (int mh = 0; mh < 2; ++mh)
#pragma unroll
        for (int r = 0; r < 4; ++r) {
            float c = c0p[16 * mh + 4 * g4 + r];
            c1[r][mh] = c; c2[r][mh] = c; hsum[r][mh] = 0.0f;
        }

    // ---------- x pipeline: xf = packed x(t), xn = raw x(t+1) ----------
    float xn[8];
    bf16x8 xf;
    {
        const float* xp = X + (size_t)batch * NI;   // t=0
        int xw[4];
#pragma unroll
        for (int q = 0; q < 4; ++q) {
            int k = k0 + 2 * q;
            float lo = (k     < NI) ? xp[k]     : 0.0f;
            float hi = (k + 1 < NI) ? xp[k + 1] : 0.0f;
            xw[q] = pack2(lo, hi);
        }
        i32x4 xv = { xw[0], xw[1], xw[2], xw[3] };
        xf = __builtin_bit_cast(bf16x8, xv);
        const float* xp1 = X + ((size_t)NB + batch) * NI;  // t=1
#pragma unroll
        for (int j = 0; j < 8; ++j) { int k = k0 + j; xn[j] = (k < NI) ? xp1[k] : 0.0f; }
    }

    // ---------- prologue: L0 gates for t=0 ----------
    f32x4 gL0[8];
#pragma unroll
    for (int m = 0; m < 8; ++m) gL0[m] = MFMA(A0x[m], xf, b0[m]);
#pragma unroll
    for (int m = 0; m < 8; ++m) gL0[m] = MFMA(A0h[m], h1f, gL0[m]);

#pragma unroll 1
    for (int t = 0; t < NT; ++t) {
        // 1. act0: h1(t) from gL0
        float hn1[4][2];
#pragma unroll
        for (int mh = 0; mh < 2; ++mh)
#pragma unroll
            for (int r = 0; r < 4; ++r) {
                float iv = sigm(gL0[0 + mh][r]);
                float fv = sigm(gL0[2 + mh][r]);
                float gv = tanh_(gL0[4 + mh][r]);
                float ov = sigm(gL0[6 + mh][r]);
                float c  = fmaf(fv, c1[r][mh], iv * gv);
                c1[r][mh] = c;
                hn1[r][mh] = ov * tanh_(c);
            }
        // 2. redist h1 -> B-frag (DS latency partially hidden by step 3)
        h1f = redist(hn1, a0, a1, mhi);

        // 3. pack xf(t+1) from xn (independent VALU, fills redist shadow)
        {
            int xw[4];
#pragma unroll
            for (int q = 0; q < 4; ++q) xw[q] = pack2(xn[2 * q], xn[2 * q + 1]);
            i32x4 xv = { xw[0], xw[1], xw[2], xw[3] };
            xf = __builtin_bit_cast(bf16x8, xv);
        }

        // 4. L1(t) gate MFMAs
        f32x4 gL1[8];
#pragma unroll
        for (int m = 0; m < 8; ++m) gL1[m] = MFMA(A1i[m], h1f, b1[m]);
#pragma unroll
        for (int m = 0; m < 8; ++m) gL1[m] = MFMA(A1h[m], h2f, gL1[m]);

        // 5. L0(t+1) gate MFMAs — independent of act1; latency hides under it
        if (t + 1 < NT) {
#pragma unroll
            for (int m = 0; m < 8; ++m) gL0[m] = MFMA(A0x[m], xf, b0[m]);
#pragma unroll
            for (int m = 0; m < 8; ++m) gL0[m] = MFMA(A0h[m], h1f, gL0[m]);
        }

        // 6. prefetch xn = x(t+2) (global, consumed 2 iters later)
        if (t + 2 < NT) {
            const float* xp = X + ((size_t)(t + 2) * NB + batch) * NI;
#pragma unroll
            for (int j = 0; j < 8; ++j) { int k = k0 + j; xn[j] = (k < NI) ? xp[k] : 0.0f; }
        }

        // 7. act1: h2(t) from gL1 (runs under gL0' MFMA shadow)
        float hn2[4][2];
#pragma unroll
        for (int mh = 0; mh < 2; ++mh)
#pragma unroll
            for (int r = 0; r < 4; ++r) {
                float iv = sigm(gL1[0 + mh][r]);
                float fv = sigm(gL1[2 + mh][r]);
                float gv = tanh_(gL1[4 + mh][r]);
                float ov = sigm(gL1[6 + mh][r]);
                float c  = fmaf(fv, c2[r][mh], iv * gv);
                c2[r][mh] = c;
                float h = ov * tanh_(c);
                hn2[r][mh] = h;
                hsum[r][mh] += h;
            }
        // 8. redist h2 -> h2f; next use is step 4 of t+1 (latency hidden by act0)
        h2f = redist(hn2, a0, a1, mhi);
    }

    // ---------- fc head ----------
    float hs[4][2];
#pragma unroll
    for (int mh = 0; mh < 2; ++mh)
#pragma unroll
        for (int r = 0; r < 4; ++r) hs[r][mh] = hsum[r][mh] * (1.0f / NT);
    bf16x8 hsf = redist(hs, a0, a1, mhi);

    int gw[4];
    {
        const float* gp = Gu + (size_t)batch * NG;
#pragma unroll
        for (int q = 0; q < 4; ++q) {
            int k = k0 + 2 * q;
            float lo = (k     < NG) ? gp[k]     : 0.0f;
            float hi = (k + 1 < NG) ? gp[k + 1] : 0.0f;
            gw[q] = pack2(lo, hi);
        }
    }
    i32x4 gv_ = { gw[0], gw[1], gw[2], gw[3] };
    bf16x8 guf = __builtin_bit_cast(bf16x8, gv_);

    f32x4 zero4 = { 0.0f, 0.0f, 0.0f, 0.0f };
    f32x4 L[2];
#pragma unroll
    for (int m2 = 0; m2 < 2; ++m2) L[m2] = MFMA(Afc0[m2], hsf, zero4);
#pragma unroll
    for (int m2 = 0; m2 < 2; ++m2) L[m2] = MFMA(Afc1[m2], guf, L[m2]);

#pragma unroll
    for (int m2 = 0; m2 < 2; ++m2)
#pragma unroll
        for (int r = 0; r < 4; ++r) {
            int row = 16 * m2 + 4 * g4 + r;
            if (row < NG) {
                float v = L[m2][r] + bfc[row];
                out[(size_t)batch * NG + row] = v;
                out[(size_t)NB * NG + (size_t)batch * NG + row] = sigm(v);
            }
        }
}

extern "C" void kernel_launch(void* const* d_in, const int* in_sizes, int n_in,
                              void* d_out, int out_size, void* d_ws, size_t ws_size,
                              hipStream_t stream) {
    const float* X    = (const float*)d_in[0];
    const float* Gu   = (const float*)d_in[1];
    const float* H0   = (const float*)d_in[2];
    const float* C0   = (const float*)d_in[3];
    const float* Wih0 = (const float*)d_in[4];
    const float* Whh0 = (const float*)d_in[5];
    const float* bih0 = (const float*)d_in[6];
    const float* bhh0 = (const float*)d_in[7];
    const float* Wih1 = (const float*)d_in[8];
    const float* Whh1 = (const float*)d_in[9];
    const float* bih1 = (const float*)d_in[10];
    const float* bhh1 = (const float*)d_in[11];
    const float* Wfc  = (const float*)d_in[12];
    const float* bfc  = (const float*)d_in[13];
    float* out = (float*)d_out;

    dim3 grid(NB / 16 / 4), block(256);  // 1024 waves, 1/SIMD, no barriers
    hipLaunchKernelGGL(lstm_pipe, grid, block, 0, stream,
                       X, Gu, H0, C0, Wih0, Whh0, bih0, bhh0,
                       Wih1, Whh1, bih1, bhh1, Wfc, bfc, out);
}

// Round 8
// 76.809 us; speedup vs baseline: 1.1631x; 1.0402x over previous
//
#include <hip/hip_runtime.h>
#include <hip/hip_bf16.h>

#define NB 16384
#define NT 32
#define NI 27
#define NH 32
#define NG 26

typedef __attribute__((ext_vector_type(8))) short bf16x8;
typedef __attribute__((ext_vector_type(4))) float f32x4;
typedef __attribute__((ext_vector_type(4))) int   i32x4;

#define MFMA(a, b, c) __builtin_amdgcn_mfma_f32_16x16x32_bf16((a), (b), (c), 0, 0, 0)

static __device__ __forceinline__ int pack2(float lo, float hi) {
    unsigned short a = __builtin_bit_cast(unsigned short, __float2bfloat16(lo));
    unsigned short b = __builtin_bit_cast(unsigned short, __float2bfloat16(hi));
    return (int)(((unsigned)b << 16) | (unsigned)a);
}

static __device__ __forceinline__ float sigm(float x) {
    return __builtin_amdgcn_rcpf(1.0f + __expf(-x));
}
static __device__ __forceinline__ float tanh_(float x) {
    return 2.0f * __builtin_amdgcn_rcpf(1.0f + __expf(-2.0f * x)) - 1.0f;
}

// MFMA A-fragment: lane (bl,g4) supplies row, k=8*g4+j from row-major
// W[nrows][rowlen], zero-padded outside. Mapping verified (R2/R4 passed).
static __device__ __forceinline__ bf16x8 load_wfrag(const float* __restrict__ W,
                                                    int rowlen, int nrows, int row, int k0) {
    int w[4];
#pragma unroll
    for (int q = 0; q < 4; ++q) {
        int k = k0 + 2 * q;
        float lo = (row < nrows && k     < rowlen) ? W[row * rowlen + k]     : 0.0f;
        float hi = (row < nrows && k + 1 < rowlen) ? W[row * rowlen + k + 1] : 0.0f;
        w[q] = pack2(lo, hi);
    }
    i32x4 v = { w[0], w[1], w[2], w[3] };
    return __builtin_bit_cast(bf16x8, v);
}

// Redistribute lane-local h_new into the B-fragment layout (verified R2/R4).
static __device__ __forceinline__ bf16x8 redist(const float hn[4][2], int a0, int a1, bool mhi) {
    int w00 = pack2(hn[0][0], hn[1][0]);
    int w01 = pack2(hn[2][0], hn[3][0]);
    int w10 = pack2(hn[0][1], hn[1][1]);
    int w11 = pack2(hn[2][1], hn[3][1]);
    int q0lo = __builtin_amdgcn_ds_bpermute(a0, w00), q0hi = __builtin_amdgcn_ds_bpermute(a0, w10);
    int q1lo = __builtin_amdgcn_ds_bpermute(a0, w01), q1hi = __builtin_amdgcn_ds_bpermute(a0, w11);
    int q2lo = __builtin_amdgcn_ds_bpermute(a1, w00), q2hi = __builtin_amdgcn_ds_bpermute(a1, w10);
    int q3lo = __builtin_amdgcn_ds_bpermute(a1, w01), q3hi = __builtin_amdgcn_ds_bpermute(a1, w11);
    i32x4 v = { mhi ? q0hi : q0lo, mhi ? q1hi : q1lo, mhi ? q2hi : q2lo, mhi ? q3hi : q3lo };
    return __builtin_bit_cast(bf16x8, v);
}

// 2 waves/block, layer-specialized: wave 0 runs the layer-0 recurrence for this
// 16-batch group; wave 1 runs layer-1, skewed one step behind, consuming h1 via
// a 2-slot LDS ring. Each wave has a complete independent chain -> 2 waves/SIMD
// that actually overlap stalls (unlike R5's split-one-chain design).
__global__ __launch_bounds__(128, 2)
void lstm_ws(const float* __restrict__ X,   // [B,T,I] flat, consumed as [T,B,I]
             const float* __restrict__ Gu,  // [B,26]
             const float* __restrict__ H0, const float* __restrict__ C0,
             const float* __restrict__ Wih0, const float* __restrict__ Whh0,
             const float* __restrict__ bih0, const float* __restrict__ bhh0,
             const float* __restrict__ Wih1, const float* __restrict__ Whh1,
             const float* __restrict__ bih1, const float* __restrict__ bhh1,
             const float* __restrict__ Wfc, const float* __restrict__ bfc,
             float* __restrict__ out)
{
    const int lane = threadIdx.x & 63;
    const int s    = threadIdx.x >> 6;   // 0 = layer-0 wave, 1 = layer-1 wave
    const int bl   = lane & 15;
    const int g4   = lane >> 4;
    const int k0   = 8 * g4;
    const int batch = blockIdx.x * 16 + bl;
    const bool mhi = (g4 >> 1) != 0;
    const int a0 = 4 * (bl + 16 * (2 * (g4 & 1)));
    const int a1 = a0 + 64;

    __shared__ i32x4 hls[2][64];   // h1 B-fragment ring: [slot][lane]

    // ---------- layer-selected weights (one load path, no duplication) ----------
    const float* Wxp = s ? Wih1 : Wih0;  const int xlen = s ? NH : NI;
    const float* Whp = s ? Whh1 : Whh0;
    const float* bip = s ? bih1 : bih0;
    const float* bhp = s ? bhh1 : bhh0;

    bf16x8 Wxf[8], Whf[8];
    f32x4  bias[8];
#pragma unroll
    for (int m = 0; m < 8; ++m) {
        Wxf[m] = load_wfrag(Wxp, xlen, 4 * NH, 16 * m + bl, k0);
        Whf[m] = load_wfrag(Whp, NH,   4 * NH, 16 * m + bl, k0);
#pragma unroll
        for (int r = 0; r < 4; ++r) {
            int gr = 16 * m + 4 * g4 + r;
            bias[m][r] = bip[gr] + bhp[gr];
        }
    }

    // ---------- state init (both layers alias h0/c0 per reference) ----------
    const float* h0p = H0 + (size_t)batch * NH;
    const float* c0p = C0 + (size_t)batch * NH;
    int hw[4];
#pragma unroll
    for (int q = 0; q < 4; ++q) hw[q] = pack2(h0p[k0 + 2 * q], h0p[k0 + 2 * q + 1]);
    i32x4 hv = { hw[0], hw[1], hw[2], hw[3] };
    bf16x8 hfrag = __builtin_bit_cast(bf16x8, hv);   // A: h1 ; B: h2
    float cst[4][2], hsum[4][2];
#pragma unroll
    for (int mh = 0; mh < 2; ++mh)
#pragma unroll
        for (int r = 0; r < 4; ++r) {
            cst[r][mh] = c0p[16 * mh + 4 * g4 + r];
            hsum[r][mh] = 0.0f;
        }

    // A-only: x prefetch buffer (raw f32 for t=0)
    float xn[8];
    if (s == 0) {
        const float* xp = X + (size_t)batch * NI;
#pragma unroll
        for (int j = 0; j < 8; ++j) { int k = k0 + j; xn[j] = (k < NI) ? xp[k] : 0.0f; }
    }

    // B-only: FC weight fragments
    bf16x8 Afc0[2], Afc1[2];
    if (s) {
#pragma unroll
        for (int m2 = 0; m2 < 2; ++m2) {
            Afc0[m2] = load_wfrag(Wfc, NH + NG, NG, 16 * m2 + bl, k0);
            Afc1[m2] = load_wfrag(Wfc, NH + NG, NG, 16 * m2 + bl, NH + k0);
        }
    }

    // ---------- main skewed loop: A handles t=it (it<NT); B handles t=it-1 (it>=1) ----------
#pragma unroll 1
    for (int it = 0; it <= NT; ++it) {
        const bool active = s ? (it >= 1) : (it < NT);
        if (active) {
            bf16x8 in;
            if (s == 0) {
                int xw[4];
#pragma unroll
                for (int q = 0; q < 4; ++q) xw[q] = pack2(xn[2 * q], xn[2 * q + 1]);
                i32x4 xv = { xw[0], xw[1], xw[2], xw[3] };
                in = __builtin_bit_cast(bf16x8, xv);
                if (it + 1 < NT) {  // prefetch next x; full iteration of cover
                    const float* xp = X + ((size_t)(it + 1) * NB + batch) * NI;
#pragma unroll
                    for (int j = 0; j < 8; ++j) { int k = k0 + j; xn[j] = (k < NI) ? xp[k] : 0.0f; }
                }
            } else {
                // h1(t-1): written by A before the previous barrier
                in = __builtin_bit_cast(bf16x8, hls[(it - 1) & 1][lane]);
            }

            // gates = Wh*hfrag + b, then += Wx*in  (Wh first: covers B's ds_read)
            f32x4 g[8];
#pragma unroll
            for (int m = 0; m < 8; ++m) g[m] = MFMA(Whf[m], hfrag, bias[m]);
#pragma unroll
            for (int m = 0; m < 8; ++m) g[m] = MFMA(Wxf[m], in, g[m]);

            float hn[4][2];
#pragma unroll
            for (int mh = 0; mh < 2; ++mh)
#pragma unroll
                for (int r = 0; r < 4; ++r) {
                    float iv = sigm(g[0 + mh][r]);
                    float fv = sigm(g[2 + mh][r]);
                    float gv = tanh_(g[4 + mh][r]);
                    float ov = sigm(g[6 + mh][r]);
                    float c  = fmaf(fv, cst[r][mh], iv * gv);
                    cst[r][mh] = c;
                    float h = ov * tanh_(c);
                    hn[r][mh] = h;
                    hsum[r][mh] += h;   // meaningful for B; dead for A (cheap)
                }
            hfrag = redist(hn, a0, a1, mhi);
            if (s == 0) hls[it & 1][lane] = __builtin_bit_cast(i32x4, hfrag);
        }
        __syncthreads();
        // ring safety: in iter it, A writes slot it&1, B reads slot (it-1)&1 — disjoint;
        // A's next write to slot (it+1)&1 happens after this barrier, which B's read preceded.
    }

    // ---------- fc head (B only; owns hsum) ----------
    if (s) {
        float hs[4][2];
#pragma unroll
        for (int mh = 0; mh < 2; ++mh)
#pragma unroll
            for (int r = 0; r < 4; ++r) hs[r][mh] = hsum[r][mh] * (1.0f / NT);
        bf16x8 hsf = redist(hs, a0, a1, mhi);

        int gw[4];
        const float* gp = Gu + (size_t)batch * NG;
#pragma unroll
        for (int q = 0; q < 4; ++q) {
            int k = k0 + 2 * q;
            float lo = (k     < NG) ? gp[k]     : 0.0f;
            float hi = (k + 1 < NG) ? gp[k + 1] : 0.0f;
            gw[q] = pack2(lo, hi);
        }
        i32x4 gv_ = { gw[0], gw[1], gw[2], gw[3] };
        bf16x8 guf = __builtin_bit_cast(bf16x8, gv_);

        f32x4 zero4 = { 0.0f, 0.0f, 0.0f, 0.0f };
        f32x4 L[2];
#pragma unroll
        for (int m2 = 0; m2 < 2; ++m2) L[m2] = MFMA(Afc0[m2], hsf, zero4);
#pragma unroll
        for (int m2 = 0; m2 < 2; ++m2) L[m2] = MFMA(Afc1[m2], guf, L[m2]);

#pragma unroll
        for (int m2 = 0; m2 < 2; ++m2)
#pragma unroll
            for (int r = 0; r < 4; ++r) {
                int row = 16 * m2 + 4 * g4 + r;
                if (row < NG) {
                    float v = L[m2][r] + bfc[row];
                    out[(size_t)batch * NG + row] = v;
                    out[(size_t)NB * NG + (size_t)batch * NG + row] = sigm(v);
                }
            }
    }
}

extern "C" void kernel_launch(void* const* d_in, const int* in_sizes, int n_in,
                              void* d_out, int out_size, void* d_ws, size_t ws_size,
                              hipStream_t stream) {
    const float* X    = (const float*)d_in[0];
    const float* Gu   = (const float*)d_in[1];
    const float* H0   = (const float*)d_in[2];
    const float* C0   = (const float*)d_in[3];
    const float* Wih0 = (const float*)d_in[4];
    const float* Whh0 = (const float*)d_in[5];
    const float* bih0 = (const float*)d_in[6];
    const float* bhh0 = (const float*)d_in[7];
    const float* Wih1 = (const float*)d_in[8];
    const float* Whh1 = (const float*)d_in[9];
    const float* bih1 = (const float*)d_in[10];
    const float* bhh1 = (const float*)d_in[11];
    const float* Wfc  = (const float*)d_in[12];
    const float* bfc  = (const float*)d_in[13];
    float* out = (float*)d_out;

    dim3 grid(NB / 16), block(128);  // 1024 blocks x 2 layer-waves = 2048 waves (2/SIMD)
    hipLaunchKernelGGL(lstm_ws, grid, block, 0, stream,
                       X, Gu, H0, C0, Wih0, Whh0, bih0, bhh0,
                       Wih1, Whh1, bih1, bhh1, Wfc, bfc, out);
}

// Round 9
// 72.585 us; speedup vs baseline: 1.2308x; 1.0582x over previous
//
#include <hip/hip_runtime.h>
#include <hip/hip_bf16.h>

#define NB 16384
#define NT 32
#define NI 27
#define NH 32
#define NG 26

typedef __attribute__((ext_vector_type(8))) short bf16x8;
typedef __attribute__((ext_vector_type(4))) float f32x4;
typedef __attribute__((ext_vector_type(4))) int   i32x4;

#define MFMA(a, b, c) __builtin_amdgcn_mfma_f32_16x16x32_bf16((a), (b), (c), 0, 0, 0)

static __device__ __forceinline__ int pack2(float lo, float hi) {
    unsigned short a = __builtin_bit_cast(unsigned short, __float2bfloat16(lo));
    unsigned short b = __builtin_bit_cast(unsigned short, __float2bfloat16(hi));
    return (int)(((unsigned)b << 16) | (unsigned)a);
}

// MFMA A-fragment loader. perm=false: lane supplies cols k0+2q, k0+2q+1 (k0=8*g4).
// perm=true: columns permuted by pi(8*g4+j) = 16*(j>>2) + 4*g4 + (j&3), so that the
// matching B-operand can be packed directly from act-layout registers (no redist).
// Sum_s W[g][pi(s)]*h[pi(s)] == Sum_k W[g][k]*h[k] (pi bijective) -> exact.
static __device__ __forceinline__ bf16x8 load_wfrag(const float* __restrict__ W,
                                                    int rowlen, int nrows, int row,
                                                    int g4, int kbase, bool perm) {
    int w[4];
#pragma unroll
    for (int q = 0; q < 4; ++q) {
        int klo = perm ? (16 * (q >> 1) + 4 * g4 + ((2 * q) & 3))
                       : (kbase + 8 * g4 + 2 * q);
        int khi = klo + 1;
        float lo = (row < nrows && klo < rowlen) ? W[row * rowlen + klo] : 0.0f;
        float hi = (row < nrows && khi < rowlen) ? W[row * rowlen + khi] : 0.0f;
        w[q] = pack2(lo, hi);
    }
    i32x4 v = { w[0], w[1], w[2], w[3] };
    return __builtin_bit_cast(bf16x8, v);
}

// act-layout (hn[r][mh] = value for hidden unit 16*mh+4*g4+r) -> B-fragment in
// pi-order: slot j = mh*4+r. Pure in-lane packing, zero cross-lane traffic.
static __device__ __forceinline__ bf16x8 pack_bfrag(const float hn[4][2]) {
    i32x4 v = { pack2(hn[0][0], hn[1][0]), pack2(hn[2][0], hn[3][0]),
                pack2(hn[0][1], hn[1][1]), pack2(hn[2][1], hn[3][1]) };
    return __builtin_bit_cast(bf16x8, v);
}

__global__ __launch_bounds__(256, 1)
void lstm_pi(const float* __restrict__ X,   // [B,T,I] flat, consumed as [T,B,I]
             const float* __restrict__ Gu,  // [B,26]
             const float* __restrict__ H0, const float* __restrict__ C0,
             const float* __restrict__ Wih0, const float* __restrict__ Whh0,
             const float* __restrict__ bih0, const float* __restrict__ bhh0,
             const float* __restrict__ Wih1, const float* __restrict__ Whh1,
             const float* __restrict__ bih1, const float* __restrict__ bhh1,
             const float* __restrict__ Wfc, const float* __restrict__ bfc,
             float* __restrict__ out)
{
    const int lane = threadIdx.x & 63;
    const int bl   = lane & 15;        // batch slot (MFMA col)
    const int g4   = lane >> 4;        // 4-lane group (K/row group)
    const int k0   = 8 * g4;
    const int wid  = blockIdx.x * (blockDim.x >> 6) + (threadIdx.x >> 6);
    const int batch = wid * 16 + bl;

    // ---------- persistent weights: h-consumers loaded with pi-permuted columns ----------
    bf16x8 A0x[8], A0h[8], A1i[8], A1h[8];
    f32x4  b0[8], b1[8];
#pragma unroll
    for (int m = 0; m < 8; ++m) {
        A0x[m] = load_wfrag(Wih0, NI, 4 * NH, 16 * m + bl, g4, 0, false);
        A0h[m] = load_wfrag(Whh0, NH, 4 * NH, 16 * m + bl, g4, 0, true);
        A1i[m] = load_wfrag(Wih1, NH, 4 * NH, 16 * m + bl, g4, 0, true);
        A1h[m] = load_wfrag(Whh1, NH, 4 * NH, 16 * m + bl, g4, 0, true);
#pragma unroll
        for (int r = 0; r < 4; ++r) {
            int gr = 16 * m + 4 * g4 + r;
            b0[m][r] = bih0[gr] + bhh0[gr];
            b1[m][r] = bih1[gr] + bhh1[gr];
        }
    }
    bf16x8 Afc0[2], Afc1[2];
#pragma unroll
    for (int m2 = 0; m2 < 2; ++m2) {
        Afc0[m2] = load_wfrag(Wfc, NH + NG, NG, 16 * m2 + bl, g4, 0, true);   // hsum part (pi)
        Afc1[m2] = load_wfrag(Wfc, NH + NG, NG, 16 * m2 + bl, g4, NH, false); // guessed part
    }

    // ---------- state init (init aliases h0/c0 for both layers); h frags in pi-order ----------
    const float* h0p = H0 + (size_t)batch * NH;
    const float* c0p = C0 + (size_t)batch * NH;
    {
        // pi-order init: word q packs units 16*(q>>1) + 4*g4 + {(2q)&3, (2q)&3+1}
    }
    i32x4 hv = { pack2(h0p[4 * g4],      h0p[4 * g4 + 1]),
                 pack2(h0p[4 * g4 + 2],  h0p[4 * g4 + 3]),
                 pack2(h0p[16 + 4 * g4], h0p[16 + 4 * g4 + 1]),
                 pack2(h0p[16 + 4 * g4 + 2], h0p[16 + 4 * g4 + 3]) };
    bf16x8 h1f = __builtin_bit_cast(bf16x8, hv);
    bf16x8 h2f = h1f;
    float c1[4][2], c2[4][2], hsum[4][2];
#pragma unroll
    for (int mh = 0; mh < 2; ++mh)
#pragma unroll
        for (int r = 0; r < 4; ++r) {
            float c = c0p[16 * mh + 4 * g4 + r];
            c1[r][mh] = c; c2[r][mh] = c; hsum[r][mh] = 0.0f;
        }

    // x prefetch (t=0)
    float xn[8];
    {
        const float* xp = X + (size_t)batch * NI;
#pragma unroll
        for (int j = 0; j < 8; ++j) { int k = k0 + j; xn[j] = (k < NI) ? xp[k] : 0.0f; }
    }

#pragma unroll 1
    for (int t = 0; t < NT; ++t) {
        int xw[4];
#pragma unroll
        for (int q = 0; q < 4; ++q) xw[q] = pack2(xn[2 * q], xn[2 * q + 1]);
        i32x4 xv = { xw[0], xw[1], xw[2], xw[3] };
        bf16x8 xf = __builtin_bit_cast(bf16x8, xv);
        if (t + 1 < NT) {
            const float* xp = X + ((size_t)(t + 1) * NB + batch) * NI;
#pragma unroll
            for (int j = 0; j < 8; ++j) { int k = k0 + j; xn[j] = (k < NI) ? xp[k] : 0.0f; }
        }

        f32x4 g[8];
        // ---------- layer 0 ----------
#pragma unroll
        for (int m = 0; m < 8; ++m) g[m] = MFMA(A0x[m], xf, b0[m]);
#pragma unroll
        for (int m = 0; m < 8; ++m) g[m] = MFMA(A0h[m], h1f, g[m]);
        float hn1[4][2];
#pragma unroll
        for (int mh = 0; mh < 2; ++mh)
#pragma unroll
            for (int r = 0; r < 4; ++r) {
                float ei = __expf(-g[0 + mh][r]);          // i
                float ef = __expf(-g[2 + mh][r]);          // f
                float eg = __expf(-2.0f * g[4 + mh][r]);   // g (tanh)
                float eo = __expf(-g[6 + mh][r]);          // o
                // i*g = (1-eg) / ((1+ei)(1+eg)); f = 1/(1+ef)
                float ig = (1.0f - eg) * __builtin_amdgcn_rcpf(fmaf(ei, eg, ei) + eg + 1.0f);
                float fv = __builtin_amdgcn_rcpf(1.0f + ef);
                float c  = fmaf(fv, c1[r][mh], ig);
                c1[r][mh] = c;
                float ec = __expf(-2.0f * c);
                // h = o*tanh(c) = (1-ec) / ((1+eo)(1+ec))
                hn1[r][mh] = (1.0f - ec) * __builtin_amdgcn_rcpf(fmaf(eo, ec, eo) + ec + 1.0f);
            }
        h1f = pack_bfrag(hn1);   // pi-order: no cross-lane redistribution needed

        // ---------- layer 1 ----------
#pragma unroll
        for (int m = 0; m < 8; ++m) g[m] = MFMA(A1i[m], h1f, b1[m]);
#pragma unroll
        for (int m = 0; m < 8; ++m) g[m] = MFMA(A1h[m], h2f, g[m]);
        float hn2[4][2];
#pragma unroll
        for (int mh = 0; mh < 2; ++mh)
#pragma unroll
            for (int r = 0; r < 4; ++r) {
                float ei = __expf(-g[0 + mh][r]);
                float ef = __expf(-g[2 + mh][r]);
                float eg = __expf(-2.0f * g[4 + mh][r]);
                float eo = __expf(-g[6 + mh][r]);
                float ig = (1.0f - eg) * __builtin_amdgcn_rcpf(fmaf(ei, eg, ei) + eg + 1.0f);
                float fv = __builtin_amdgcn_rcpf(1.0f + ef);
                float c  = fmaf(fv, c2[r][mh], ig);
                c2[r][mh] = c;
                float ec = __expf(-2.0f * c);
                float h  = (1.0f - ec) * __builtin_amdgcn_rcpf(fmaf(eo, ec, eo) + ec + 1.0f);
                hn2[r][mh] = h;
                hsum[r][mh] += h;
            }
        h2f = pack_bfrag(hn2);
    }

    // ---------- fc head: logits = Wfc_pi[:, :32]*(hsum/T) + Wfc[:, 32:]*Gu + bfc ----------
    float hs[4][2];
#pragma unroll
    for (int mh = 0; mh < 2; ++mh)
#pragma unroll
        for (int r = 0; r < 4; ++r) hs[r][mh] = hsum[r][mh] * (1.0f / NT);
    bf16x8 hsf = pack_bfrag(hs);

    int gw[4];
    {
        const float* gp = Gu + (size_t)batch * NG;
#pragma unroll
        for (int q = 0; q < 4; ++q) {
            int k = k0 + 2 * q;
            float lo = (k     < NG) ? gp[k]     : 0.0f;
            float hi = (k + 1 < NG) ? gp[k + 1] : 0.0f;
            gw[q] = pack2(lo, hi);
        }
    }
    i32x4 gv_ = { gw[0], gw[1], gw[2], gw[3] };
    bf16x8 guf = __builtin_bit_cast(bf16x8, gv_);

    f32x4 zero4 = { 0.0f, 0.0f, 0.0f, 0.0f };
    f32x4 L[2];
#pragma unroll
    for (int m2 = 0; m2 < 2; ++m2) L[m2] = MFMA(Afc0[m2], hsf, zero4);
#pragma unroll
    for (int m2 = 0; m2 < 2; ++m2) L[m2] = MFMA(Afc1[m2], guf, L[m2]);

#pragma unroll
    for (int m2 = 0; m2 < 2; ++m2)
#pragma unroll
        for (int r = 0; r < 4; ++r) {
            int row = 16 * m2 + 4 * g4 + r;
            if (row < NG) {
                float v = L[m2][r] + bfc[row];
                out[(size_t)batch * NG + row] = v;
                out[(size_t)NB * NG + (size_t)batch * NG + row] =
                    __builtin_amdgcn_rcpf(1.0f + __expf(-v));
            }
        }
}

extern "C" void kernel_launch(void* const* d_in, const int* in_sizes, int n_in,
                              void* d_out, int out_size, void* d_ws, size_t ws_size,
                              hipStream_t stream) {
    const float* X    = (const float*)d_in[0];
    const float* Gu   = (const float*)d_in[1];
    const float* H0   = (const float*)d_in[2];
    const float* C0   = (const float*)d_in[3];
    const float* Wih0 = (const float*)d_in[4];
    const float* Whh0 = (const float*)d_in[5];
    const float* bih0 = (const float*)d_in[6];
    const float* bhh0 = (const float*)d_in[7];
    const float* Wih1 = (const float*)d_in[8];
    const float* Whh1 = (const float*)d_in[9];
    const float* bih1 = (const float*)d_in[10];
    const float* bhh1 = (const float*)d_in[11];
    const float* Wfc  = (const float*)d_in[12];
    const float* bfc  = (const float*)d_in[13];
    float* out = (float*)d_out;

    dim3 grid(NB / 16 / 4), block(256);  // 1024 waves, 1/SIMD, zero DS/LDS traffic
    hipLaunchKernelGGL(lstm_pi, grid, block, 0, stream,
                       X, Gu, H0, C0, Wih0, Whh0, bih0, bhh0,
                       Wih1, Whh1, bih1, bhh1, Wfc, bfc, out);
}